// Round 4
// baseline (205.069 us; speedup 1.0000x reference)
//
#include <hip/hip_runtime.h>
#include <math.h>

// Problem constants: B molecules, N=64 atoms, E=512 edges, R_CUT=10
#define SQRT_PI 1.7724538509055160273
#define SQRT_2  1.4142135623730950488
#define PI_OVER_2RC 0.15707963267948966
#define W0 32.0   // w-threshold: edges with w>W0 get exact f64 Gram contribution

// ws layout (doubles), B = #molecules:
//   Spart : [2][B][4096]   per-slice Gram partials
//   t0p   : [2][B][128]    per-slice T(w*b) | T(w*1) partials
//   w     : [B][512]
//   b     : [B][512]
//   sa/sb : [B][128]
// total = B * 9600 doubles = 19.66 MB @ B=256

__device__ __forceinline__ double bcast64(double v, int lane) {
    union { double d; unsigned int u[2]; } a, r;
    a.d = v;
    r.u[0] = __builtin_amdgcn_readlane(a.u[0], lane);
    r.u[1] = __builtin_amdgcn_readlane(a.u[1], lane);
    return r.d;
}

__device__ __forceinline__ double a_entry(int i, int j, const double* posd,
                                          const double* sig, const double* dg) {
    if (i == j) return dg[i];
    double dx = posd[3*i+0]-posd[3*j+0];
    double dy = posd[3*i+1]-posd[3*j+1];
    double dz = posd[3*i+2]-posd[3*j+2];
    double d  = sqrt(dx*dx+dy*dy+dz*dz);
    double g  = sqrt(sig[i]+sig[j]);
    return erf(d/(SQRT_2*g))/d;
}

// ---------------- K1: per-(mol, slice) Gram + w,b,t0 ----------------
// f32 Gram for w<=W0 edges (sqrt(w)-scaled T, promote to f64 every 16 edges)
// + exact f64 correction for the rare w>W0 edges. b and t0 in f64 (raw T).
__global__ __launch_bounds__(256, 2)
void k1_gram(const float* __restrict__ pos, const float* __restrict__ T,
             const float* __restrict__ eneg, const int* __restrict__ eidx,
             double* __restrict__ ws)
{
    const int bx = blockIdx.x;
    const int m = bx >> 1, s = bx & 1;
    const int Bm = gridDim.x >> 1;
    const int tid = threadIdx.x;

    __shared__ float  Tch[64*68];      // raw then sqrt(w)-scaled T chunk
    __shared__ double posd[192];
    __shared__ double eneg_s[64];
    __shared__ double w_sl[256];       // w (unclamped, f64) for slice edges
    __shared__ float  sw32[256];       // sqrt(w) clamped: 0 for flagged edges
    __shared__ double wb[64];          // w*b for current chunk
    __shared__ double ptr_[2][4][64];  // t0 reduction scratch
    __shared__ unsigned long long fmask[4];  // per-chunk flagged-edge masks

    const float* Tm = T + (size_t)m*64*512;
    double* wv = ws + (size_t)2*Bm*4096 + (size_t)2*Bm*128 + (size_t)m*512;
    double* bv = wv + (size_t)Bm*512;

    if (tid < 64) {
        posd[3*tid+0] = (double)pos[(m*64+tid)*3+0];
        posd[3*tid+1] = (double)pos[(m*64+tid)*3+1];
        posd[3*tid+2] = (double)pos[(m*64+tid)*3+2];
        eneg_s[tid]   = (double)eneg[m*64+tid];
    }
    __syncthreads();

    // per-edge w = 1/cut for this slice (1 edge/thread), f64
    {
        const int e = s*256 + tid;
        const int a0 = eidx[(size_t)m*1024 + e];
        const int a1 = eidx[(size_t)m*1024 + 512 + e];
        double dx = posd[3*a0+0]-posd[3*a1+0];
        double dy = posd[3*a0+1]-posd[3*a1+1];
        double dz = posd[3*a0+2]-posd[3*a1+2];
        double d  = sqrt(dx*dx+dy*dy+dz*dz);
        double w  = 1.0 / (1.0/cos(PI_OVER_2RC*d) - 1.0);
        wv[e] = w;
        w_sl[tid] = w;
        sw32[tid] = (w > W0) ? 0.0f : (float)sqrt(w);
    }
    __syncthreads();
    if (tid < 64) {
        #pragma unroll
        for (int c2 = 0; c2 < 4; ++c2) {
            unsigned long long mk = __ballot(w_sl[c2*64 + tid] > W0);
            if (tid == 0) fmask[c2] = mk;
        }
    }

    const int si = tid & 15, sj = tid >> 4;
    const int ti = tid & 63, tg = tid >> 6;

    const int PP_[10] = {0,0,0,0,1,1,1,2,2,3};
    const int QQ_[10] = {0,1,2,3,1,2,3,2,3,3};
    double acc64[10];
    float  a32[10];
    #pragma unroll
    for (int k = 0; k < 10; ++k) { acc64[k] = 0.0; a32[k] = 0.0f; }
    double t0a_p = 0.0, t0b_p = 0.0;

    for (int cc = 0; cc < 4; ++cc) {
        const int gch = s*4 + cc;
        __syncthreads();    // prev chunk reads done; fmask visible (cc=0)
        #pragma unroll
        for (int k = 0; k < 4; ++k) {
            int l = tid + 256*k, row = l >> 4, c4 = (l & 15)*4;
            float4 v = *(const float4*)&Tm[row*512 + gch*64 + c4];
            *(float4*)&Tch[row*68 + c4] = v;
        }
        __syncthreads();
        // b dots (raw T, f64): 4 threads per edge
        {
            int ed = tid >> 2, part = tid & 3;
            double a = 0.0;
            #pragma unroll
            for (int ii = 0; ii < 16; ++ii) {
                int i = part*16 + ii;
                a += (double)Tch[i*68 + ed] * eneg_s[i];
            }
            a += __shfl_down(a, 2);
            a += __shfl_down(a, 1);
            if (part == 0) {
                double b = -a;
                bv[s*256 + cc*64 + ed] = b;
                wb[ed] = w_sl[cc*64 + ed] * b;
            }
        }
        __syncthreads();
        // t0 partials (raw T, f64)
        #pragma unroll
        for (int k = 0; k < 16; ++k) {
            int e = tg*16 + k;
            double tv = (double)Tch[ti*68 + e];
            t0a_p += tv * wb[e];
            t0b_p += tv * w_sl[cc*64 + e];
        }
        // flagged heavy edges: exact f64 rank-1 contributions (raw T)
        {
            unsigned long long mm = fmask[cc];
            while (mm) {
                int e = __builtin_ctzll(mm); mm &= mm - 1;
                double we = w_sl[cc*64 + e];
                double ad[4], bd[4];
                #pragma unroll
                for (int p = 0; p < 4; ++p) ad[p] = (double)Tch[(si+16*p)*68 + e];
                #pragma unroll
                for (int q = 0; q < 4; ++q) bd[q] = we * (double)Tch[(sj+16*q)*68 + e];
                #pragma unroll
                for (int k = 0; k < 10; ++k) acc64[k] += ad[PP_[k]] * bd[QQ_[k]];
            }
        }
        __syncthreads();   // raw reads done
        // scale chunk in place by clamped sqrt(w)
        #pragma unroll
        for (int k = 0; k < 4; ++k) {
            int l = tid + 256*k, row = l >> 4, c4 = (l & 15)*4;
            float4 v = *(float4*)&Tch[row*68 + c4];
            v.x *= sw32[cc*64 + c4+0];
            v.y *= sw32[cc*64 + c4+1];
            v.z *= sw32[cc*64 + c4+2];
            v.w *= sw32[cc*64 + c4+3];
            *(float4*)&Tch[row*68 + c4] = v;
        }
        __syncthreads();
        // f32 Gram (10 sym tiles), promote every 16 edges
        #pragma unroll
        for (int e4 = 0; e4 < 16; ++e4) {
            float4 av4[4], bv4[4];
            #pragma unroll
            for (int p = 0; p < 4; ++p) av4[p] = *(float4*)&Tch[(si+16*p)*68 + e4*4];
            #pragma unroll
            for (int q = 0; q < 4; ++q) bv4[q] = *(float4*)&Tch[(sj+16*q)*68 + e4*4];
            #pragma unroll
            for (int k = 0; k < 10; ++k) {
                const float4 a4 = av4[PP_[k]], b4 = bv4[QQ_[k]];
                a32[k] += a4.x*b4.x + a4.y*b4.y + a4.z*b4.z + a4.w*b4.w;
            }
            if ((e4 & 3) == 3) {
                #pragma unroll
                for (int k = 0; k < 10; ++k) { acc64[k] += (double)a32[k]; a32[k] = 0.0f; }
            }
        }
    }
    __syncthreads();

    double* Sp = ws + ((size_t)(s*Bm + m))*4096;
    #pragma unroll
    for (int k = 0; k < 10; ++k) {
        int i = si + 16*PP_[k], j = sj + 16*QQ_[k];
        Sp[i*64 + j] = acc64[k];
        if (PP_[k] != QQ_[k]) Sp[j*64 + i] = acc64[k];
    }

    ptr_[0][tg][ti] = t0a_p;
    ptr_[1][tg][ti] = t0b_p;
    __syncthreads();
    double* t0p = ws + (size_t)2*Bm*4096 + ((size_t)(s*Bm + m))*128;
    if (tid < 64) {
        t0p[tid] = ptr_[0][0][tid]+ptr_[0][1][tid]+ptr_[0][2][tid]+ptr_[0][3][tid];
    } else if (tid < 128) {
        int i = tid - 64;
        t0p[64+i] = ptr_[1][0][i]+ptr_[1][1][i]+ptr_[1][2][i]+ptr_[1][3][i];
    }
}

// ---------------- K2: assemble M, blocked LDL^T, solve, s = A*u ----------------
// 1024 threads (16 waves/CU). A kept in registers (areg) + LDS AB.
__global__ __launch_bounds__(1024, 1)
void k2_solve(const float* __restrict__ pos, const float* __restrict__ nattr,
              const float* __restrict__ hard, const float* __restrict__ covr,
              const int* __restrict__ an, double* __restrict__ ws)
{
    const int m = blockIdx.x, tid = threadIdx.x;
    const int Bm = gridDim.x;
    const int jl = tid & 63;        // lane / column index
    const int rg = tid >> 6;        // wave id 0..15

    __shared__ double AB[64*65];    // A then M/L (stride 65: col reads 2-way)
    __shared__ double UB[64*33];    // union: SP panel [32][64] -> PP [64][33]
    __shared__ double posd[192], sig_s[64], dg_s[64];
    __shared__ double t0a_s[64], t0b_s[64], ga_s[64], gb_s[64], ua_s[64], ub_s[64];
    __shared__ double dinv_s[64], dvec_s[64];

    if (tid < 64) {
        posd[3*tid+0] = (double)pos[(m*64+tid)*3+0];
        posd[3*tid+1] = (double)pos[(m*64+tid)*3+1];
        posd[3*tid+2] = (double)pos[(m*64+tid)*3+2];
        double r = (double)covr[an[m*64+tid]];
        sig_s[tid] = r*r;
        const float* np_ = nattr + (size_t)(m*64+tid)*10;
        float best = np_[0]; int bi = 0;
        #pragma unroll
        for (int k = 1; k < 10; ++k) { float v = np_[k]; if (v > best) { best = v; bi = k; } }
        dg_s[tid] = (double)hard[bi] + 1.0/(SQRT_PI*r);
    }
    const double* t0p0 = ws + (size_t)2*Bm*4096 + (size_t)m*128;
    const double* t0p1 = ws + (size_t)2*Bm*4096 + (size_t)(Bm + m)*128;
    if (tid >= 64 && tid < 192) {
        int l = tid - 64;
        double v = t0p0[l] + t0p1[l];
        if (l < 64) t0a_s[l] = v; else t0b_s[l-64] = v;
    }
    __syncthreads();

    // build A: thread owns rows i = rg+16p, column jl
    double areg[4];
    #pragma unroll
    for (int p = 0; p < 4; ++p) {
        int i = rg + 16*p;
        double v = a_entry(i, jl, posd, sig_s, dg_s);
        areg[p] = v;
        AB[i*65 + jl] = v;
    }
    __syncthreads();

    // g = A*t0 via full-wave reduction (each wave produces rows rg+16p)
    {
        double ra[4], rb[4];
        const double ta = t0a_s[jl], tb = t0b_s[jl];
        #pragma unroll
        for (int p = 0; p < 4; ++p) { ra[p] = areg[p]*ta; rb[p] = areg[p]*tb; }
        #pragma unroll
        for (int off = 32; off > 0; off >>= 1) {
            #pragma unroll
            for (int p = 0; p < 4; ++p) {
                ra[p] += __shfl_down(ra[p], off);
                rb[p] += __shfl_down(rb[p], off);
            }
        }
        if (jl == 0) {
            #pragma unroll
            for (int p = 0; p < 4; ++p) { ga_s[rg+16*p] = ra[p]; gb_s[rg+16*p] = rb[p]; }
        }
    }

    // M = A + A*S*A, accumulated in registers (M[i][jl], i = rg+16p)
    double macc[4];
    #pragma unroll
    for (int p = 0; p < 4; ++p) macc[p] = areg[p];

    const double* Sp0 = ws + (size_t)m*4096;
    const double* Sp1 = ws + (size_t)(Bm + m)*4096;
    for (int pass = 0; pass < 2; ++pass) {
        const int kbase = pass*32;
        __syncthreads();                 // UB free
        for (int l = tid; l < 2048; l += 1024) {
            int c = l >> 6, k = l & 63;  // SP[c][k] = S[kbase+c][k] (S symmetric)
            UB[c*64 + k] = Sp0[(size_t)(kbase+c)*64 + k] + Sp1[(size_t)(kbase+c)*64 + k];
        }
        __syncthreads();
        // P[jl][kbase+c] = sum_k A[jl][k] * S[k][kbase+c]; c-pair per wave
        const int c0 = 2*rg, c1 = c0 + 1;
        double p0 = 0.0, p1 = 0.0;
        #pragma unroll 4
        for (int k = 0; k < 64; ++k) {
            double a = AB[jl*65 + k];          // column read, 2-way banks
            p0 += a * UB[c0*64 + k];           // broadcast
            p1 += a * UB[c1*64 + k];           // broadcast
        }
        __syncthreads();                 // SP reads done
        UB[jl*33 + c0] = p0;             // PP[jl][c-local]
        UB[jl*33 + c1] = p1;
        __syncthreads();
        // macc[p] += sum_c P[rg+16p][c] * A[kbase+c][jl]
        #pragma unroll 4
        for (int cl = 0; cl < 32; ++cl) {
            double lb = AB[(kbase+cl)*65 + jl];    // row read
            #pragma unroll
            for (int p = 0; p < 4; ++p)
                macc[p] += UB[(rg+16*p)*33 + cl] * lb;  // broadcasts
        }
    }
    __syncthreads();
    #pragma unroll
    for (int p = 0; p < 4; ++p) AB[(rg+16*p)*65 + jl] = macc[p];   // AB = M
    __syncthreads();

    // blocked LDL^T: 16-col panels factored in wave0, trailing by all 16 waves
    for (int pb = 0; pb < 4; ++pb) {
        const int kb = pb*16;
        if (tid < 64) {
            const int i = tid;
            double pr[16];
            #pragma unroll
            for (int c = 0; c < 16; ++c) pr[c] = AB[i*65 + kb + c];
            #pragma unroll
            for (int c = 0; c < 16; ++c) {
                const int k = kb + c;
                const double Dk = bcast64(pr[c], k);
                const double di = 1.0 / Dk;
                if (i == k) { dinv_s[k] = di; dvec_s[k] = Dk; }
                const double lik = pr[c] * di;
                #pragma unroll
                for (int j = c+1; j < 16; ++j) {
                    const double mkj = bcast64(pr[j], k);
                    if (i > k) pr[j] -= lik * mkj;
                }
                if (i > k) pr[c] = lik;
            }
            #pragma unroll
            for (int c = 0; c < 16; ++c) AB[i*65 + kb + c] = pr[c];
        }
        __syncthreads();
        const int lim = kb + 16;
        if (lim < 64) {
            double tacc[4] = {0.0, 0.0, 0.0, 0.0};
            #pragma unroll 4
            for (int c = 0; c < 16; ++c) {
                double lbv = AB[jl*65 + kb + c] * dvec_s[kb + c];   // col read
                #pragma unroll
                for (int p = 0; p < 4; ++p)
                    tacc[p] += AB[(rg+16*p)*65 + kb + c] * lbv;     // broadcast
            }
            if (jl >= lim) {
                #pragma unroll
                for (int p = 0; p < 4; ++p) {
                    int i = rg + 16*p;
                    if (i >= lim) AB[i*65 + jl] -= tacc[p];
                }
            }
        }
        __syncthreads();
    }

    // solves in wave0: L h = g ; h *= D^-1 ; L^T u = h
    if (tid < 64) {
        const int i = tid;
        double ha = ga_s[i], hb = gb_s[i];
        #pragma unroll
        for (int j = 0; j < 63; ++j) {
            double xa = bcast64(ha, j), xb = bcast64(hb, j);
            double lij = (i > j) ? AB[i*65+j] : 0.0;
            ha -= lij*xa; hb -= lij*xb;
        }
        double di = dinv_s[i];
        ha *= di; hb *= di;
        #pragma unroll
        for (int j = 63; j > 0; --j) {
            double xa = bcast64(ha, j), xb = bcast64(hb, j);
            double lji = (i < j) ? AB[j*65+i] : 0.0;
            ha -= lji*xa; hb -= lji*xb;
        }
        ua_s[i] = ha; ub_s[i] = hb;
    }
    __syncthreads();

    // s = A*u via areg wave reduction; write straight to ws
    double* sav = ws + (size_t)2*Bm*4096 + (size_t)2*Bm*128 + (size_t)2*Bm*512 + (size_t)m*128;
    {
        double ra[4], rb[4];
        const double uaj = ua_s[jl], ubj = ub_s[jl];
        #pragma unroll
        for (int p = 0; p < 4; ++p) { ra[p] = areg[p]*uaj; rb[p] = areg[p]*ubj; }
        #pragma unroll
        for (int off = 32; off > 0; off >>= 1) {
            #pragma unroll
            for (int p = 0; p < 4; ++p) {
                ra[p] += __shfl_down(ra[p], off);
                rb[p] += __shfl_down(rb[p], off);
            }
        }
        if (jl == 0) {
            #pragma unroll
            for (int p = 0; p < 4; ++p) {
                sav[rg + 16*p]      = ra[p];
                sav[64 + rg + 16*p] = rb[p];
            }
        }
    }
}

// ---------------- K3: y/z pass, lambda, output ----------------
__global__ __launch_bounds__(512, 2)
void k3_out(const float* __restrict__ T, const float* __restrict__ qtot,
            const double* __restrict__ ws, float* __restrict__ outp)
{
    const int m = blockIdx.x, tid = threadIdx.x;
    const int Bm = gridDim.x;

    __shared__ float  Tch[64*68];
    __shared__ double w_s[512], b_s[512];
    __shared__ double sa_s[64], sb_s[64];
    __shared__ double ych[64], zch[64];
    __shared__ double syp[64], szp[64];
    __shared__ double pt[2][8][64];
    __shared__ double lam_s;

    const float* Tm = T + (size_t)m*64*512;
    const double* wv  = ws + (size_t)2*Bm*4096 + (size_t)2*Bm*128 + (size_t)m*512;
    const double* bvv = wv + (size_t)Bm*512;
    const double* sav = ws + (size_t)2*Bm*4096 + (size_t)2*Bm*128 + (size_t)2*Bm*512 + (size_t)m*128;

    w_s[tid] = wv[tid];
    b_s[tid] = bvv[tid];
    if (tid < 128) {
        if (tid < 64) sa_s[tid] = sav[tid];
        else          sb_s[tid-64] = sav[tid];
    }

    const int ed = tid >> 3, part = tid & 7;
    const int ti = tid & 63, tg = tid >> 6;
    double sY = 0.0, sZ = 0.0, p1p = 0.0, p2p = 0.0;

    for (int ch = 0; ch < 8; ++ch) {
        __syncthreads();
        #pragma unroll
        for (int k = 0; k < 2; ++k) {
            int l = tid + 512*k, row = l >> 4, c4 = (l & 15)*4;
            float4 v = *(const float4*)&Tm[row*512 + ch*64 + c4];
            *(float4*)&Tch[row*68 + c4] = v;
        }
        __syncthreads();
        {
            double da = 0.0, db = 0.0;
            #pragma unroll
            for (int ii = 0; ii < 8; ++ii) {
                int i = part*8 + ii;
                double tv = (double)Tch[i*68 + ed];
                da += tv * sa_s[i];
                db += tv * sb_s[i];
            }
            da += __shfl_down(da, 4); da += __shfl_down(da, 2); da += __shfl_down(da, 1);
            db += __shfl_down(db, 4); db += __shfl_down(db, 2); db += __shfl_down(db, 1);
            if (part == 0) {
                int e = ch*64 + ed;
                double yv = w_s[e]*(b_s[e] - da);
                double zv = w_s[e]*(1.0 - db);
                ych[ed] = yv; zch[ed] = zv;
                sY += yv; sZ += zv;
            }
        }
        __syncthreads();
        #pragma unroll
        for (int k = 0; k < 8; ++k) {
            int e = tg*8 + k;
            double tv = (double)Tch[ti*68 + e];
            p1p += tv * ych[e];
            p2p += tv * zch[e];
        }
    }
    if (part == 0) { syp[ed] = sY; szp[ed] = sZ; }
    pt[0][tg][ti] = p1p;
    pt[1][tg][ti] = p2p;
    __syncthreads();
    if (tid < 64) {
        double vy = syp[tid], vz = szp[tid];
        #pragma unroll
        for (int off = 32; off > 0; off >>= 1) {
            vy += __shfl_down(vy, off);
            vz += __shfl_down(vz, off);
        }
        if (tid == 0) lam_s = ((double)qtot[m] - vy) / (1.0 - vz);
    }
    __syncthreads();
    if (tid < 64) {
        double p1 = 0.0, p2 = 0.0;
        #pragma unroll
        for (int g = 0; g < 8; ++g) { p1 += pt[0][g][tid]; p2 += pt[1][g][tid]; }
        outp[m*64 + tid] = (float)(p1 - lam_s*p2);
    }
}

extern "C" void kernel_launch(void* const* d_in, const int* in_sizes, int n_in,
                              void* d_out, int out_size, void* d_ws, size_t ws_size,
                              hipStream_t stream) {
    const float* pos  = (const float*)d_in[0];
    const float* T    = (const float*)d_in[1];
    const float* eneg = (const float*)d_in[2];
    const float* nat  = (const float*)d_in[3];
    const float* qt   = (const float*)d_in[4];
    // d_in[5] 'p' unused
    const float* hard = (const float*)d_in[6];
    const float* covr = (const float*)d_in[7];
    const int*   an   = (const int*)d_in[8];
    const int*   eidx = (const int*)d_in[9];
    float* outp = (float*)d_out;
    (void)n_in; (void)out_size; (void)ws_size;

    const int B = in_sizes[4];
    double* ws = (double*)d_ws;   // B*9600*8 bytes = 19.7 MB @ B=256

    k1_gram<<<dim3(2*B), dim3(256), 0, stream>>>(pos, T, eneg, eidx, ws);
    k2_solve<<<dim3(B), dim3(1024), 0, stream>>>(pos, nat, hard, covr, an, ws);
    k3_out<<<dim3(B), dim3(512), 0, stream>>>(T, qt, ws, outp);
}

// Round 7
// 185.903 us; speedup vs baseline: 1.1031x; 1.1031x over previous
//
#include <hip/hip_runtime.h>
#include <math.h>

// Problem constants: B molecules, N=64 atoms, E=512 edges, R_CUT=10
#define SQRT_PI 1.7724538509055160273
#define SQRT_2  1.4142135623730950488
#define PI_OVER_2RC 0.15707963267948966
#define W0 32.0   // edges with w>W0 get exact f64 Gram contribution

// ws layout (doubles), B = #molecules:
//   Spart : [2][B][4096]   per-slice Gram partials
//   t0bp  : [2][B][64]     per-slice T·w partials
//   swp   : [2][B]         per-slice sum(w)
// total = B*8322 doubles ≈ 17 MB @ B=256

__device__ __forceinline__ double bcast64(double v, int lane) {
    union { double d; unsigned int u[2]; } a, r;
    a.d = v;
    r.u[0] = __builtin_amdgcn_readlane(a.u[0], lane);
    r.u[1] = __builtin_amdgcn_readlane(a.u[1], lane);
    return r.d;
}

__device__ __forceinline__ double a_entry(int i, int j, const double* posd,
                                          const double* sig, const double* dg) {
    if (i == j) return dg[i];
    double dx = posd[3*i+0]-posd[3*j+0];
    double dy = posd[3*i+1]-posd[3*j+1];
    double dz = posd[3*i+2]-posd[3*j+2];
    double d  = sqrt(dx*dx+dy*dy+dz*dz);
    double g  = sqrt(sig[i]+sig[j]);
    return erf(d/(SQRT_2*g))/d;
}

// ---------------- K1: per-(mol, slice) Gram + w,t0b,sw1 ----------------
// f32 Gram for w<=W0 edges (sqrt(w)-scaled T, f64 promote every 16 edges)
// + exact f64 rank-1 for w>W0 edges. t0b = T·w in f64 (raw T).
__global__ __launch_bounds__(256, 2)
void k1_gram(const float* __restrict__ pos, const float* __restrict__ T,
             const int* __restrict__ eidx, double* __restrict__ ws)
{
    const int bx = blockIdx.x;
    const int m = bx >> 1, s = bx & 1;
    const int Bm = gridDim.x >> 1;
    const int tid = threadIdx.x;

    __shared__ float  Tch[64*68];      // raw then sqrt(w)-scaled T chunk
    __shared__ double posd[192];
    __shared__ double w_sl[256];       // w (unclamped, f64) for slice edges
    __shared__ float  sw32[256];       // sqrt(w) clamped: 0 for flagged edges
    __shared__ double ptb[4][64];      // t0b reduction scratch
    __shared__ unsigned long long fmask[4];  // per-chunk flagged-edge masks

    const float* Tm = T + (size_t)m*64*512;

    if (tid < 64) {
        posd[3*tid+0] = (double)pos[(m*64+tid)*3+0];
        posd[3*tid+1] = (double)pos[(m*64+tid)*3+1];
        posd[3*tid+2] = (double)pos[(m*64+tid)*3+2];
    }
    __syncthreads();

    // per-edge w = 1/cut for this slice (1 edge/thread), f64
    {
        const int e = s*256 + tid;
        const int a0 = eidx[(size_t)m*1024 + e];
        const int a1 = eidx[(size_t)m*1024 + 512 + e];
        double dx = posd[3*a0+0]-posd[3*a1+0];
        double dy = posd[3*a0+1]-posd[3*a1+1];
        double dz = posd[3*a0+2]-posd[3*a1+2];
        double d  = sqrt(dx*dx+dy*dy+dz*dz);
        double w  = 1.0 / (1.0/cos(PI_OVER_2RC*d) - 1.0);
        w_sl[tid] = w;
        sw32[tid] = (w > W0) ? 0.0f : (float)sqrt(w);
    }
    __syncthreads();
    if (tid < 64) {
        #pragma unroll
        for (int c2 = 0; c2 < 4; ++c2) {
            unsigned long long mk = __ballot(w_sl[c2*64 + tid] > W0);
            if (tid == 0) fmask[c2] = mk;
        }
    }

    const int si = tid & 15, sj = tid >> 4;
    const int ti64 = tid & 63, tg = tid >> 6;

    const int PP_[10] = {0,0,0,0,1,1,1,2,2,3};
    const int QQ_[10] = {0,1,2,3,1,2,3,2,3,3};
    double acc64[10];
    float  a32[10];
    #pragma unroll
    for (int k = 0; k < 10; ++k) { acc64[k] = 0.0; a32[k] = 0.0f; }
    double t0b_p = 0.0;

    for (int cc = 0; cc < 4; ++cc) {
        const int gch = s*4 + cc;
        __syncthreads();    // prev chunk reads done; fmask visible (cc=0)
        #pragma unroll
        for (int k = 0; k < 4; ++k) {
            int l = tid + 256*k, row = l >> 4, c4 = (l & 15)*4;
            float4 v = *(const float4*)&Tm[row*512 + gch*64 + c4];
            *(float4*)&Tch[row*68 + c4] = v;
        }
        __syncthreads();
        // t0b partials (raw T, f64)
        #pragma unroll
        for (int k = 0; k < 16; ++k) {
            int e = tg*16 + k;
            double tv = (double)Tch[ti64*68 + e];
            t0b_p += tv * w_sl[cc*64 + e];
        }
        // flagged heavy edges: exact f64 rank-1 contributions (raw T)
        {
            unsigned long long mm = fmask[cc];
            while (mm) {
                int e = __builtin_ctzll(mm); mm &= mm - 1;
                double we = w_sl[cc*64 + e];
                double ad[4], bd[4];
                #pragma unroll
                for (int p = 0; p < 4; ++p) ad[p] = (double)Tch[(si+16*p)*68 + e];
                #pragma unroll
                for (int q = 0; q < 4; ++q) bd[q] = we * (double)Tch[(sj+16*q)*68 + e];
                #pragma unroll
                for (int k = 0; k < 10; ++k) acc64[k] += ad[PP_[k]] * bd[QQ_[k]];
            }
        }
        __syncthreads();   // raw reads done
        // scale chunk in place by clamped sqrt(w)
        #pragma unroll
        for (int k = 0; k < 4; ++k) {
            int l = tid + 256*k, row = l >> 4, c4 = (l & 15)*4;
            float4 v = *(float4*)&Tch[row*68 + c4];
            v.x *= sw32[cc*64 + c4+0];
            v.y *= sw32[cc*64 + c4+1];
            v.z *= sw32[cc*64 + c4+2];
            v.w *= sw32[cc*64 + c4+3];
            *(float4*)&Tch[row*68 + c4] = v;
        }
        __syncthreads();
        // f32 Gram (10 sym tiles), promote every 16 edges
        #pragma unroll
        for (int e4 = 0; e4 < 16; ++e4) {
            float4 av4[4], bv4[4];
            #pragma unroll
            for (int p = 0; p < 4; ++p) av4[p] = *(float4*)&Tch[(si+16*p)*68 + e4*4];
            #pragma unroll
            for (int q = 0; q < 4; ++q) bv4[q] = *(float4*)&Tch[(sj+16*q)*68 + e4*4];
            #pragma unroll
            for (int k = 0; k < 10; ++k) {
                const float4 a4 = av4[PP_[k]], b4 = bv4[QQ_[k]];
                a32[k] += a4.x*b4.x + a4.y*b4.y + a4.z*b4.z + a4.w*b4.w;
            }
            if ((e4 & 3) == 3) {
                #pragma unroll
                for (int k = 0; k < 10; ++k) { acc64[k] += (double)a32[k]; a32[k] = 0.0f; }
            }
        }
    }
    __syncthreads();

    double* Sp = ws + ((size_t)(s*Bm + m))*4096;
    #pragma unroll
    for (int k = 0; k < 10; ++k) {
        int i = si + 16*PP_[k], j = sj + 16*QQ_[k];
        Sp[i*64 + j] = acc64[k];
        if (PP_[k] != QQ_[k]) Sp[j*64 + i] = acc64[k];
    }

    ptb[tg][ti64] = t0b_p;
    __syncthreads();
    if (tid < 64) {
        double* t0q = ws + (size_t)2*Bm*4096;
        t0q[(size_t)(s*Bm + m)*64 + tid] =
            ptb[0][tid]+ptb[1][tid]+ptb[2][tid]+ptb[3][tid];
        double sw = w_sl[tid] + w_sl[64+tid] + w_sl[128+tid] + w_sl[192+tid];
        #pragma unroll
        for (int off = 32; off > 0; off >>= 1) sw += __shfl_down(sw, off);
        if (tid == 0) {
            double* swq = ws + (size_t)2*Bm*4096 + (size_t)2*Bm*64;
            swq[s*Bm + m] = sw;
        }
    }
}

// ---------------- K2: M = A + A*S*A, blocked LDL^T, solve, fused output ----------------
// 1024 threads = 16 waves. Epilogue: t0a = -S·eneg, p1 = t0a - S·sa,
// p2 = t0b - S·sb, lam = (q + t0b·(eneg+sa)) / (1 - sw1 + t0b·sb),
// out = p1 - lam*p2.
__global__ __launch_bounds__(1024)
void k2_solve(const float* __restrict__ pos, const float* __restrict__ nattr,
              const float* __restrict__ eneg, const float* __restrict__ qtot,
              const float* __restrict__ hard, const float* __restrict__ covr,
              const int* __restrict__ an, double* __restrict__ ws,
              float* __restrict__ outp)
{
    const int m = blockIdx.x, tid = threadIdx.x;
    const int Bm = gridDim.x;
    const int jl = tid & 63;        // lane
    const int rg = tid >> 6;        // wave id 0..15

    __shared__ double AB[64*65];    // A then M/L
    __shared__ double PB[64*33];    // GEMM staging + matvec scratch (2112 doubles)
    __shared__ double posd[192], sig_s[64], dg_s[64], eneg_s[64];
    __shared__ double t0a_s[64], t0b_s[64], ga_s[64], gb_s[64], ua_s[64], ub_s[64];
    __shared__ double sa_s[64], sb_s[64];
    __shared__ double dinv_s[64], dvec_s[64];
    __shared__ double lam_sh;

    const double* Sp0 = ws + (size_t)m*4096;
    const double* Sp1 = ws + (size_t)(Bm + m)*4096;
    const double* t0q = ws + (size_t)2*Bm*4096;
    const double* swq = t0q + (size_t)2*Bm*64;

    if (tid < 64) {
        posd[3*tid+0] = (double)pos[(m*64+tid)*3+0];
        posd[3*tid+1] = (double)pos[(m*64+tid)*3+1];
        posd[3*tid+2] = (double)pos[(m*64+tid)*3+2];
        double r = (double)covr[an[m*64+tid]];
        sig_s[tid] = r*r;
        const float* np_ = nattr + (size_t)(m*64+tid)*10;
        float best = np_[0]; int bi = 0;
        #pragma unroll
        for (int k = 1; k < 10; ++k) { float v = np_[k]; if (v > best) { best = v; bi = k; } }
        dg_s[tid] = (double)hard[bi] + 1.0/(SQRT_PI*r);
    } else if (tid < 128) {
        int l = tid - 64;
        t0b_s[l] = t0q[(size_t)m*64 + l] + t0q[(size_t)(Bm+m)*64 + l];
    } else if (tid < 192) {
        int l = tid - 128;
        eneg_s[l] = (double)eneg[m*64 + l];
    }
    __syncthreads();

    // build A: thread holds rows rg+16p at column jl (areg) and fills AB
    double areg[4];
    #pragma unroll
    for (int p = 0; p < 4; ++p) {
        int i = rg + 16*p;
        double v = a_entry(i, jl, posd, sig_s, dg_s);
        areg[p] = v;
        AB[i*65 + jl] = v;
    }

    // t0a = -S·eneg: partials into PB[16][64]
    {
        int i = tid & 63, kg = tid >> 6;
        double a = 0.0;
        #pragma unroll
        for (int kk = 0; kk < 4; ++kk) {
            int k = 4*kg + kk;
            a += (Sp0[i*64+k] + Sp1[i*64+k]) * eneg_s[k];
        }
        PB[kg*64 + i] = a;
    }
    __syncthreads();   // AB complete + PB partials complete
    if (tid < 64) {
        double a = 0.0;
        #pragma unroll
        for (int g = 0; g < 16; ++g) a += PB[g*64 + tid];
        t0a_s[tid] = -a;
    }
    __syncthreads();

    // g = A·t0 via wave reduction (wave rg produces rows rg+16p)
    {
        double ra[4], rb[4];
        const double ta = t0a_s[jl], tb = t0b_s[jl];
        #pragma unroll
        for (int p = 0; p < 4; ++p) { ra[p] = areg[p]*ta; rb[p] = areg[p]*tb; }
        #pragma unroll
        for (int off = 32; off > 0; off >>= 1) {
            #pragma unroll
            for (int p = 0; p < 4; ++p) {
                ra[p] += __shfl_down(ra[p], off);
                rb[p] += __shfl_down(rb[p], off);
            }
        }
        if (jl == 0) {
            #pragma unroll
            for (int p = 0; p < 4; ++p) { ga_s[rg+16*p] = ra[p]; gb_s[rg+16*p] = rb[p]; }
        }
    }

    // M = A + A*S*A, accumulated in registers (M[rg+16p][jl])
    double macc[4];
    #pragma unroll
    for (int p = 0; p < 4; ++p) macc[p] = areg[p];

    for (int pass = 0; pass < 2; ++pass) {
        const int kbase = pass*32;
        __syncthreads();                 // PB free
        for (int l2 = tid; l2 < 2048; l2 += 1024) {
            int c = l2 >> 6, k = l2 & 63;  // SP[c][k] = S[kbase+c][k] (S symmetric)
            PB[c*64 + k] = Sp0[(size_t)(kbase+c)*64 + k] + Sp1[(size_t)(kbase+c)*64 + k];
        }
        __syncthreads();
        // P[jl][kbase+c] = sum_k A[jl][k] * S[k][kbase+c]; c-pair per wave
        const int c0 = 2*rg, c1 = c0 + 1;
        double p0 = 0.0, p1 = 0.0;
        #pragma unroll 4
        for (int k = 0; k < 64; ++k) {
            double a = AB[jl*65 + k];
            p0 += a * PB[c0*64 + k];
            p1 += a * PB[c1*64 + k];
        }
        __syncthreads();                 // SP reads done
        PB[jl*33 + c0] = p0;
        PB[jl*33 + c1] = p1;
        __syncthreads();
        // macc[p] += sum_c P[rg+16p][c] * A[kbase+c][jl]
        #pragma unroll 4
        for (int cl = 0; cl < 32; ++cl) {
            double lb = AB[(kbase+cl)*65 + jl];
            #pragma unroll
            for (int p = 0; p < 4; ++p)
                macc[p] += PB[(rg+16*p)*33 + cl] * lb;
        }
    }
    __syncthreads();
    #pragma unroll
    for (int p = 0; p < 4; ++p) AB[(rg+16*p)*65 + jl] = macc[p];   // AB = M
    __syncthreads();

    // blocked LDL^T: 16-col panels factored in wave0, trailing by all 16 waves
    for (int pb = 0; pb < 4; ++pb) {
        const int kb = pb*16;
        if (tid < 64) {
            const int i = tid;
            double pr[16];
            #pragma unroll
            for (int c = 0; c < 16; ++c) pr[c] = AB[i*65 + kb + c];
            #pragma unroll
            for (int c = 0; c < 16; ++c) {
                const int k = kb + c;
                const double Dk = bcast64(pr[c], k);
                const double di = 1.0 / Dk;
                if (i == k) { dinv_s[k] = di; dvec_s[k] = Dk; }
                const double lik = pr[c] * di;
                #pragma unroll
                for (int j = c+1; j < 16; ++j) {
                    const double mkj = bcast64(pr[j], k);
                    if (i > k) pr[j] -= lik * mkj;
                }
                if (i > k) pr[c] = lik;
            }
            #pragma unroll
            for (int c = 0; c < 16; ++c) AB[i*65 + kb + c] = pr[c];
        }
        __syncthreads();
        const int lim = kb + 16;
        if (lim < 64) {
            double tacc[4] = {0.0, 0.0, 0.0, 0.0};
            #pragma unroll 4
            for (int c = 0; c < 16; ++c) {
                double lbv = AB[jl*65 + kb + c] * dvec_s[kb + c];
                #pragma unroll
                for (int p = 0; p < 4; ++p)
                    tacc[p] += AB[(rg+16*p)*65 + kb + c] * lbv;
            }
            if (jl >= lim) {
                #pragma unroll
                for (int p = 0; p < 4; ++p) {
                    int i = rg + 16*p;
                    if (i >= lim) AB[i*65 + jl] -= tacc[p];
                }
            }
        }
        __syncthreads();
    }

    // solves in wave0: L h = g ; h *= D^-1 ; L^T u = h
    if (tid < 64) {
        const int i = tid;
        double ha = ga_s[i], hb = gb_s[i];
        #pragma unroll
        for (int j = 0; j < 63; ++j) {
            double xa = bcast64(ha, j), xb = bcast64(hb, j);
            double lij = (i > j) ? AB[i*65+j] : 0.0;
            ha -= lij*xa; hb -= lij*xb;
        }
        double di = dinv_s[i];
        ha *= di; hb *= di;
        #pragma unroll
        for (int j = 63; j > 0; --j) {
            double xa = bcast64(ha, j), xb = bcast64(hb, j);
            double lji = (i < j) ? AB[j*65+i] : 0.0;
            ha -= lji*xa; hb -= lji*xb;
        }
        ua_s[i] = ha; ub_s[i] = hb;
    }
    __syncthreads();

    // s = A·u via areg wave reduction → sa_s/sb_s
    {
        double ra[4], rb[4];
        const double uaj = ua_s[jl], ubj = ub_s[jl];
        #pragma unroll
        for (int p = 0; p < 4; ++p) { ra[p] = areg[p]*uaj; rb[p] = areg[p]*ubj; }
        #pragma unroll
        for (int off = 32; off > 0; off >>= 1) {
            #pragma unroll
            for (int p = 0; p < 4; ++p) {
                ra[p] += __shfl_down(ra[p], off);
                rb[p] += __shfl_down(rb[p], off);
            }
        }
        if (jl == 0) {
            #pragma unroll
            for (int p = 0; p < 4; ++p) {
                sa_s[rg + 16*p] = ra[p];
                sb_s[rg + 16*p] = rb[p];
            }
        }
    }
    __syncthreads();

    // S·sa and S·sb partials into PB[0..1023] / PB[1024..2047]
    {
        int i = tid & 63, kg = tid >> 6;
        double a1 = 0.0, a2 = 0.0;
        #pragma unroll
        for (int kk = 0; kk < 4; ++kk) {
            int k = 4*kg + kk;
            double Sv = Sp0[i*64+k] + Sp1[i*64+k];
            a1 += Sv * sa_s[k];
            a2 += Sv * sb_s[k];
        }
        PB[kg*64 + i] = a1;
        PB[1024 + kg*64 + i] = a2;
    }
    // lambda dots (wave0, concurrent with matvec partial writes)
    if (tid < 64) {
        double d1 = (eneg_s[tid] + sa_s[tid]) * t0b_s[tid];
        double d2 = sb_s[tid] * t0b_s[tid];
        #pragma unroll
        for (int off = 32; off > 0; off >>= 1) {
            d1 += __shfl_down(d1, off);
            d2 += __shfl_down(d2, off);
        }
        if (tid == 0) {
            double sw1 = swq[m] + swq[Bm + m];
            double sY = -d1;               // sY = -t0b·(eneg+sa)
            double sZ = sw1 - d2;          // sZ = sw1 - t0b·sb
            lam_sh = ((double)qtot[m] - sY) / (1.0 - sZ);
        }
    }
    __syncthreads();
    if (tid < 64) {
        double q1 = 0.0, q2 = 0.0;
        #pragma unroll
        for (int g = 0; g < 16; ++g) {
            q1 += PB[g*64 + tid];
            q2 += PB[1024 + g*64 + tid];
        }
        double p1 = t0a_s[tid] - q1;       // p1 = t0a - S·sa
        double p2 = t0b_s[tid] - q2;       // p2 = t0b - S·sb
        outp[m*64 + tid] = (float)(p1 - lam_sh*p2);
    }
}

extern "C" void kernel_launch(void* const* d_in, const int* in_sizes, int n_in,
                              void* d_out, int out_size, void* d_ws, size_t ws_size,
                              hipStream_t stream) {
    const float* pos  = (const float*)d_in[0];
    const float* T    = (const float*)d_in[1];
    const float* eneg = (const float*)d_in[2];
    const float* nat  = (const float*)d_in[3];
    const float* qt   = (const float*)d_in[4];
    // d_in[5] 'p' unused
    const float* hard = (const float*)d_in[6];
    const float* covr = (const float*)d_in[7];
    const int*   an   = (const int*)d_in[8];
    const int*   eidx = (const int*)d_in[9];
    float* outp = (float*)d_out;
    (void)n_in; (void)out_size; (void)ws_size; (void)eneg;

    const int B = in_sizes[4];
    double* ws = (double*)d_ws;   // B*8322*8 bytes ≈ 17 MB @ B=256

    k1_gram<<<dim3(2*B), dim3(256), 0, stream>>>(pos, T, eidx, ws);
    k2_solve<<<dim3(B), dim3(1024), 0, stream>>>(pos, nat, eneg, qt, hard,
                                                 covr, an, ws, outp);
}

// Round 8
// 178.343 us; speedup vs baseline: 1.1499x; 1.0424x over previous
//
#include <hip/hip_runtime.h>
#include <math.h>

// Problem constants: B molecules, N=64 atoms, E=512 edges, R_CUT=10
#define SQRT_PI 1.7724538509055160273
#define SQRT_2  1.4142135623730950488
#define PI_OVER_2RC 0.15707963267948966
#define W0 32.0   // fallback path: edges with w>W0 get exact f64 Gram contribution

typedef double dbl4 __attribute__((ext_vector_type(4)));

// ws layout (doubles), B = #molecules:
//   Spart : [2][B][4096]  t0bp : [2][B][64]  swp : [2][B]
//   flags : 5 doubles at ws + B*8322
// total = B*8322 + 5 doubles

__device__ __forceinline__ double bcast64(double v, int lane) {
    union { double d; unsigned int u[2]; } a, r;
    a.d = v;
    r.u[0] = __builtin_amdgcn_readlane(a.u[0], lane);
    r.u[1] = __builtin_amdgcn_readlane(a.u[1], lane);
    return r.d;
}

__device__ __forceinline__ double a_entry(int i, int j, const double* posd,
                                          const double* sig, const double* dg) {
    if (i == j) return dg[i];
    double dx = posd[3*i+0]-posd[3*j+0];
    double dy = posd[3*i+1]-posd[3*j+1];
    double dz = posd[3*i+2]-posd[3*j+2];
    double d  = sqrt(dx*dx+dy*dy+dz*dz);
    double g  = sqrt(sig[i]+sig[j]);
    return erf(d/(SQRT_2*g))/d;
}

// swap-aware MFMA: xv = A-side value, yv = B-side value
__device__ __forceinline__ dbl4 mfma64(int cS, double xv, double yv, dbl4 acc) {
    return cS ? __builtin_amdgcn_mfma_f64_16x16x4f64(yv, xv, acc, 0, 0, 0)
              : __builtin_amdgcn_mfma_f64_16x16x4f64(xv, yv, acc, 0, 0, 0);
}

// ---------------- K0: f64-MFMA layout probe (injective, dual value-set) ----------------
__global__ __launch_bounds__(64)
void k0_probe(double* __restrict__ fl)
{
    const int l = threadIdx.x;
    const int kl = l >> 4, ml = l & 15;
    const double af1 = (double)(l + 1),  bf1 = (double)(l + 65);
    const double af2 = (double)(1 + ((l*7 + 3) % 61));
    const double bf2 = (double)(2 + ((l*13 + 5) % 53));
    dbl4 c1 = {0.0,0.0,0.0,0.0}, c2 = {0.0,0.0,0.0,0.0};
    c1 = __builtin_amdgcn_mfma_f64_16x16x4f64(af1, bf1, c1, 0, 0, 0);
    c2 = __builtin_amdgcn_mfma_f64_16x16x4f64(af2, bf2, c2, 0, 0, 0);
    int best = -1;
    for (int h = 0; h < 32; ++h) {
        if (best >= 0) break;
        const int cS = h >> 4, cA = (h >> 3) & 1, cB = (h >> 2) & 1, cD = h & 3;
        bool ok = true;
        #pragma unroll
        for (int r = 0; r < 4; ++r) {
            int row, col;
            const int v0 = 4*kl + r, v1 = kl + 4*r;
            if (cD == 0)      { row = v0; col = ml; }
            else if (cD == 1) { row = v1; col = ml; }
            else if (cD == 2) { row = ml; col = v0; }
            else              { row = ml; col = v1; }
            double r1 = 0.0, r2 = 0.0;
            #pragma unroll
            for (int k = 0; k < 4; ++k) {
                const int la = cA ? (row*4 + k) : (row + 16*k);
                const int lb = cB ? (col*4 + k) : (col + 16*k);
                if (cS == 0) {
                    r1 += (double)(la + 1) * (double)(lb + 65);
                    r2 += (double)(1 + ((la*7+3) % 61)) * (double)(2 + ((lb*13+5) % 53));
                } else {   // arg0 carries B (lane lb), arg1 carries A (lane la)
                    r1 += (double)(lb + 1) * (double)(la + 65);
                    r2 += (double)(1 + ((lb*7+3) % 61)) * (double)(2 + ((la*13+5) % 53));
                }
            }
            if (c1[r] != r1 || c2[r] != r2) ok = false;
        }
        if (__ballot(ok) == ~0ull) best = h;
    }
    if (l == 0) {
        fl[0] = (best >= 0) ? 1.0 : 0.0;
        fl[1] = (double)((best >= 0) ? (best >> 4)      : 0);
        fl[2] = (double)((best >= 0) ? ((best >> 3) & 1) : 0);
        fl[3] = (double)((best >= 0) ? ((best >> 2) & 1) : 0);
        fl[4] = (double)((best >= 0) ? (best & 3)        : 0);
    }
}

// ---------------- K1: per-(mol, slice) Gram + t0b, sw1 ----------------
// MFMA path: exact f64 Gram via v_mfma_f64_16x16x4 (probed layout).
// Fallback: f32 Gram for w<=W0 + exact f64 rank-1 for w>W0 (verified r7).
__global__ __launch_bounds__(256, 2)
void k1_gram(const float* __restrict__ pos, const float* __restrict__ T,
             const int* __restrict__ eidx, double* __restrict__ ws)
{
    const int bx = blockIdx.x;
    const int m = bx >> 1, s = bx & 1;
    const int Bm = gridDim.x >> 1;
    const int tid = threadIdx.x;
    const int wid = tid >> 6, l = tid & 63;
    const int kl = l >> 4, ml = l & 15;

    __shared__ float  Tch[64*68];
    __shared__ double posd[192];
    __shared__ double w_sl[256];
    __shared__ float  sw32[256];
    __shared__ double ptb[4][64];
    __shared__ unsigned long long fmask[4];

    const float* Tm = T + (size_t)m*64*512;
    const double* flq = ws + (size_t)Bm*8322;
    const int useM = (flq[0] != 0.0);
    const int cS = (int)flq[1], cA = (int)flq[2], cB = (int)flq[3], cD = (int)flq[4];
    const int aRow = cA ? (l >> 2) : ml;
    const int aK   = cA ? (l & 3)  : kl;
    const int bRow = cB ? (l >> 2) : ml;
    const int bK   = cB ? (l & 3)  : kl;
    int drow[4], dcol[4];
    #pragma unroll
    for (int r = 0; r < 4; ++r) {
        const int v0 = 4*kl + r, v1 = kl + 4*r;
        if (cD == 0)      { drow[r] = v0; dcol[r] = ml; }
        else if (cD == 1) { drow[r] = v1; dcol[r] = ml; }
        else if (cD == 2) { drow[r] = ml; dcol[r] = v0; }
        else              { drow[r] = ml; dcol[r] = v1; }
    }

    if (tid < 64) {
        posd[3*tid+0] = (double)pos[(m*64+tid)*3+0];
        posd[3*tid+1] = (double)pos[(m*64+tid)*3+1];
        posd[3*tid+2] = (double)pos[(m*64+tid)*3+2];
    }
    __syncthreads();

    {
        const int e = s*256 + tid;
        const int a0 = eidx[(size_t)m*1024 + e];
        const int a1 = eidx[(size_t)m*1024 + 512 + e];
        double dx = posd[3*a0+0]-posd[3*a1+0];
        double dy = posd[3*a0+1]-posd[3*a1+1];
        double dz = posd[3*a0+2]-posd[3*a1+2];
        double d  = sqrt(dx*dx+dy*dy+dz*dz);
        double w  = 1.0 / (1.0/cos(PI_OVER_2RC*d) - 1.0);
        w_sl[tid] = w;
        sw32[tid] = (w > W0) ? 0.0f : (float)sqrt(w);
    }
    __syncthreads();
    if (tid < 64) {
        #pragma unroll
        for (int c2 = 0; c2 < 4; ++c2) {
            unsigned long long mk = __ballot(w_sl[c2*64 + tid] > W0);
            if (tid == 0) fmask[c2] = mk;
        }
    }

    const int si = tid & 15, sj = tid >> 4;
    const int ti64 = tid & 63, tg = tid >> 6;

    // MFMA tile assignment: byte t of enc = (p<<4)|q, 0xFF unused
    const unsigned int enc = (wid==0) ? 0x020100u :
                             (wid==1) ? 0x121103u :
                             (wid==2) ? 0xFF2213u : 0xFF3323u;
    dbl4 vacc[3];
    #pragma unroll
    for (int t = 0; t < 3; ++t) vacc[t] = (dbl4){0.0, 0.0, 0.0, 0.0};

    // fallback accumulators
    const int PP_[10] = {0,0,0,0,1,1,1,2,2,3};
    const int QQ_[10] = {0,1,2,3,1,2,3,2,3,3};
    double acc64[10];
    float  a32[10];
    #pragma unroll
    for (int k = 0; k < 10; ++k) { acc64[k] = 0.0; a32[k] = 0.0f; }
    double t0b_p = 0.0;

    for (int cc = 0; cc < 4; ++cc) {
        const int gch = s*4 + cc;
        __syncthreads();
        #pragma unroll
        for (int k = 0; k < 4; ++k) {
            int ll = tid + 256*k, row = ll >> 4, c4 = (ll & 15)*4;
            float4 v = *(const float4*)&Tm[row*512 + gch*64 + c4];
            *(float4*)&Tch[row*68 + c4] = v;
        }
        __syncthreads();
        // t0b partials (raw T, f64)
        #pragma unroll
        for (int k = 0; k < 16; ++k) {
            int e = tg*16 + k;
            double tv = (double)Tch[ti64*68 + e];
            t0b_p += tv * w_sl[cc*64 + e];
        }
        if (useM) {
            // exact f64 Gram via MFMA: 16 K=4 steps over chunk's 64 edges
            for (int kk = 0; kk < 16; ++kk) {
                const double wB = w_sl[cc*64 + 4*kk + bK];
                #pragma unroll
                for (int t = 0; t < 3; ++t) {
                    const unsigned int pq = (enc >> (8*t)) & 0xFFu;
                    if (pq != 0xFFu) {
                        const int p = pq >> 4, q = pq & 15;
                        double xv = (double)Tch[(p*16 + aRow)*68 + 4*kk + aK];
                        double yv = wB * (double)Tch[(q*16 + bRow)*68 + 4*kk + bK];
                        vacc[t] = mfma64(cS, xv, yv, vacc[t]);
                    }
                }
            }
        } else {
            // flagged heavy edges: exact f64 rank-1 (raw T)
            {
                unsigned long long mm = fmask[cc];
                while (mm) {
                    int e = __builtin_ctzll(mm); mm &= mm - 1;
                    double we = w_sl[cc*64 + e];
                    double ad[4], bd[4];
                    #pragma unroll
                    for (int p = 0; p < 4; ++p) ad[p] = (double)Tch[(si+16*p)*68 + e];
                    #pragma unroll
                    for (int q = 0; q < 4; ++q) bd[q] = we * (double)Tch[(sj+16*q)*68 + e];
                    #pragma unroll
                    for (int k = 0; k < 10; ++k) acc64[k] += ad[PP_[k]] * bd[QQ_[k]];
                }
            }
            __syncthreads();
            #pragma unroll
            for (int k = 0; k < 4; ++k) {
                int ll = tid + 256*k, row = ll >> 4, c4 = (ll & 15)*4;
                float4 v = *(float4*)&Tch[row*68 + c4];
                v.x *= sw32[cc*64 + c4+0];
                v.y *= sw32[cc*64 + c4+1];
                v.z *= sw32[cc*64 + c4+2];
                v.w *= sw32[cc*64 + c4+3];
                *(float4*)&Tch[row*68 + c4] = v;
            }
            __syncthreads();
            #pragma unroll
            for (int e4 = 0; e4 < 16; ++e4) {
                float4 av4[4], bv4[4];
                #pragma unroll
                for (int p = 0; p < 4; ++p) av4[p] = *(float4*)&Tch[(si+16*p)*68 + e4*4];
                #pragma unroll
                for (int q = 0; q < 4; ++q) bv4[q] = *(float4*)&Tch[(sj+16*q)*68 + e4*4];
                #pragma unroll
                for (int k = 0; k < 10; ++k) {
                    const float4 a4 = av4[PP_[k]], b4 = bv4[QQ_[k]];
                    a32[k] += a4.x*b4.x + a4.y*b4.y + a4.z*b4.z + a4.w*b4.w;
                }
                if ((e4 & 3) == 3) {
                    #pragma unroll
                    for (int k = 0; k < 10; ++k) { acc64[k] += (double)a32[k]; a32[k] = 0.0f; }
                }
            }
        }
    }
    __syncthreads();

    double* Sp = ws + ((size_t)(s*Bm + m))*4096;
    if (useM) {
        #pragma unroll
        for (int t = 0; t < 3; ++t) {
            const unsigned int pq = (enc >> (8*t)) & 0xFFu;
            if (pq != 0xFFu) {
                const int p = pq >> 4, q = pq & 15;
                #pragma unroll
                for (int r = 0; r < 4; ++r) {
                    Sp[(p*16 + drow[r])*64 + q*16 + dcol[r]] = vacc[t][r];
                    if (p != q)
                        Sp[(q*16 + dcol[r])*64 + p*16 + drow[r]] = vacc[t][r];
                }
            }
        }
    } else {
        #pragma unroll
        for (int k = 0; k < 10; ++k) {
            int i = si + 16*PP_[k], j = sj + 16*QQ_[k];
            Sp[i*64 + j] = acc64[k];
            if (PP_[k] != QQ_[k]) Sp[j*64 + i] = acc64[k];
        }
    }

    ptb[tg][ti64] = t0b_p;
    __syncthreads();
    if (tid < 64) {
        double* t0q = ws + (size_t)2*Bm*4096;
        t0q[(size_t)(s*Bm + m)*64 + tid] =
            ptb[0][tid]+ptb[1][tid]+ptb[2][tid]+ptb[3][tid];
        double sw = w_sl[tid] + w_sl[64+tid] + w_sl[128+tid] + w_sl[192+tid];
        #pragma unroll
        for (int off = 32; off > 0; off >>= 1) sw += __shfl_down(sw, off);
        if (tid == 0) {
            double* swq = ws + (size_t)2*Bm*4096 + (size_t)2*Bm*64;
            swq[s*Bm + m] = sw;
        }
    }
}

// ---------------- K2: M = A + A*S*A, blocked LDL^T, solve, fused output ----------------
__global__ __launch_bounds__(1024)
void k2_solve(const float* __restrict__ pos, const float* __restrict__ nattr,
              const float* __restrict__ eneg, const float* __restrict__ qtot,
              const float* __restrict__ hard, const float* __restrict__ covr,
              const int* __restrict__ an, double* __restrict__ ws,
              float* __restrict__ outp)
{
    const int m = blockIdx.x, tid = threadIdx.x;
    const int Bm = gridDim.x;
    const int jl = tid & 63;        // lane
    const int rg = tid >> 6;        // wave id 0..15
    const int kl = jl >> 4, ml = jl & 15;

    __shared__ double AB[64*65];    // A then M/L
    __shared__ double PB[64*33];    // GEMM staging / P-halves / epilogue scratch
    __shared__ double posd[192], sig_s[64], dg_s[64], eneg_s[64];
    __shared__ double t0a_s[64], t0b_s[64], ga_s[64], gb_s[64], ua_s[64], ub_s[64];
    __shared__ double sa_s[64], sb_s[64];
    __shared__ double dinv_s[64], dvec_s[64];
    __shared__ double lam_sh;

    const double* Sp0 = ws + (size_t)m*4096;
    const double* Sp1 = ws + (size_t)(Bm + m)*4096;
    const double* t0q = ws + (size_t)2*Bm*4096;
    const double* swq = t0q + (size_t)2*Bm*64;
    const double* flq = ws + (size_t)Bm*8322;

    const int useM = (flq[0] != 0.0);
    const int cS = (int)flq[1], cA = (int)flq[2], cB = (int)flq[3], cD = (int)flq[4];
    const int aRow = cA ? (jl >> 2) : ml;
    const int aK   = cA ? (jl & 3)  : kl;
    const int bRow = cB ? (jl >> 2) : ml;
    const int bK   = cB ? (jl & 3)  : kl;
    int drow[4], dcol[4];
    #pragma unroll
    for (int r = 0; r < 4; ++r) {
        const int v0 = 4*kl + r, v1 = kl + 4*r;
        if (cD == 0)      { drow[r] = v0; dcol[r] = ml; }
        else if (cD == 1) { drow[r] = v1; dcol[r] = ml; }
        else if (cD == 2) { drow[r] = ml; dcol[r] = v0; }
        else              { drow[r] = ml; dcol[r] = v1; }
    }

    // coalesced register-resident Ssum: sreg[kk] = Ssum[tid>>4][4*(tid&15)+kk]
    double sreg[4];
    #pragma unroll
    for (int kk = 0; kk < 4; ++kk)
        sreg[kk] = Sp0[4*tid + kk] + Sp1[4*tid + kk];

    if (tid < 64) {
        posd[3*tid+0] = (double)pos[(m*64+tid)*3+0];
        posd[3*tid+1] = (double)pos[(m*64+tid)*3+1];
        posd[3*tid+2] = (double)pos[(m*64+tid)*3+2];
        double r = (double)covr[an[m*64+tid]];
        sig_s[tid] = r*r;
        const float* np_ = nattr + (size_t)(m*64+tid)*10;
        float best = np_[0]; int bi = 0;
        #pragma unroll
        for (int k = 1; k < 10; ++k) { float v = np_[k]; if (v > best) { best = v; bi = k; } }
        dg_s[tid] = (double)hard[bi] + 1.0/(SQRT_PI*r);
    } else if (tid < 128) {
        int ll = tid - 64;
        t0b_s[ll] = t0q[(size_t)m*64 + ll] + t0q[(size_t)(Bm+m)*64 + ll];
    } else if (tid < 192) {
        int ll = tid - 128;
        eneg_s[ll] = (double)eneg[m*64 + ll];
    }
    __syncthreads();

    // build A: thread holds rows rg+16p at column jl (areg) and fills AB
    double areg[4];
    #pragma unroll
    for (int p = 0; p < 4; ++p) {
        int i = rg + 16*p;
        double v = a_entry(i, jl, posd, sig_s, dg_s);
        areg[p] = v;
        AB[i*65 + jl] = v;
    }
    // t0a = -S·eneg via sreg + 16-lane reduce
    {
        const int c16 = tid & 15, row16 = tid >> 4;
        double a = 0.0;
        #pragma unroll
        for (int kk = 0; kk < 4; ++kk) a += sreg[kk] * eneg_s[4*c16 + kk];
        a += __shfl_down(a, 8, 16);
        a += __shfl_down(a, 4, 16);
        a += __shfl_down(a, 2, 16);
        a += __shfl_down(a, 1, 16);
        if (c16 == 0) t0a_s[row16] = -a;
    }
    __syncthreads();

    // g = A·t0 via wave reduction
    {
        double ra[4], rb[4];
        const double ta = t0a_s[jl], tb = t0b_s[jl];
        #pragma unroll
        for (int p = 0; p < 4; ++p) { ra[p] = areg[p]*ta; rb[p] = areg[p]*tb; }
        #pragma unroll
        for (int off = 32; off > 0; off >>= 1) {
            #pragma unroll
            for (int p = 0; p < 4; ++p) {
                ra[p] += __shfl_down(ra[p], off);
                rb[p] += __shfl_down(rb[p], off);
            }
        }
        if (jl == 0) {
            #pragma unroll
            for (int p = 0; p < 4; ++p) { ga_s[rg+16*p] = ra[p]; gb_s[rg+16*p] = rb[p]; }
        }
    }
    __syncthreads();

    if (useM) {
        // ---- MFMA GEMMs, pass-split (P half: 32 cols, stride 33) ----
        const int ti1 = rg >> 2;                 // GEMM1 tile row
        const int tjp = (rg & 3) >> 1;           // GEMM1 tile col within pass (0..1)
        const int kh  = rg & 1;                  // k-half
        const int ti2 = rg >> 2, tj2 = rg & 3;   // GEMM2 tile
        dbl4 macc;
        #pragma unroll
        for (int r = 0; r < 4; ++r)
            macc[r] = AB[(ti2*16 + drow[r])*65 + tj2*16 + dcol[r]];
        for (int pass = 0; pass < 2; ++pass) {
            const int kbase = pass*32;
            dbl4 pacc = {0.0, 0.0, 0.0, 0.0};
            #pragma unroll
            for (int kk = 0; kk < 8; ++kk) {
                const int kg = kh*8 + kk;        // K=4 block index 0..15
                double xv = AB[(ti1*16 + aRow)*65 + 4*kg + aK];
                size_t so = (size_t)(4*kg + bK)*64 + kbase + tjp*16 + bRow;
                double yv = Sp0[so] + Sp1[so];
                pacc = mfma64(cS, xv, yv, pacc);
            }
            __syncthreads();   // prev-pass PB reads done
            if (kh == 0) {
                #pragma unroll
                for (int r = 0; r < 4; ++r)
                    PB[(ti1*16 + drow[r])*33 + tjp*16 + dcol[r]] = pacc[r];
            }
            __syncthreads();
            if (kh == 1) {
                #pragma unroll
                for (int r = 0; r < 4; ++r)
                    PB[(ti1*16 + drow[r])*33 + tjp*16 + dcol[r]] += pacc[r];
            }
            __syncthreads();   // P-half complete
            #pragma unroll
            for (int kk = 0; kk < 8; ++kk) {
                double xv = PB[(ti2*16 + aRow)*33 + 4*kk + aK];
                double yv = AB[(kbase + 4*kk + bK)*65 + tj2*16 + bRow];
                macc = mfma64(cS, xv, yv, macc);
            }
        }
        __syncthreads();   // all GEMM2 AB reads done
        #pragma unroll
        for (int r = 0; r < 4; ++r)
            AB[(ti2*16 + drow[r])*65 + tj2*16 + dcol[r]] = macc[r];
        __syncthreads();
    } else {
        // ---- VALU fallback (verified r4/r7) ----
        double macc[4];
        #pragma unroll
        for (int p = 0; p < 4; ++p) macc[p] = areg[p];
        for (int pass = 0; pass < 2; ++pass) {
            const int kbase = pass*32;
            __syncthreads();
            for (int l2 = tid; l2 < 2048; l2 += 1024) {
                int c = l2 >> 6, k = l2 & 63;
                PB[c*64 + k] = Sp0[(size_t)(kbase+c)*64 + k] + Sp1[(size_t)(kbase+c)*64 + k];
            }
            __syncthreads();
            const int c0 = 2*rg, c1 = c0 + 1;
            double p0 = 0.0, p1 = 0.0;
            #pragma unroll 4
            for (int k = 0; k < 64; ++k) {
                double a = AB[jl*65 + k];
                p0 += a * PB[c0*64 + k];
                p1 += a * PB[c1*64 + k];
            }
            __syncthreads();
            PB[jl*33 + c0] = p0;
            PB[jl*33 + c1] = p1;
            __syncthreads();
            #pragma unroll 4
            for (int cl = 0; cl < 32; ++cl) {
                double lb = AB[(kbase+cl)*65 + jl];
                #pragma unroll
                for (int p = 0; p < 4; ++p)
                    macc[p] += PB[(rg+16*p)*33 + cl] * lb;
            }
        }
        __syncthreads();
        #pragma unroll
        for (int p = 0; p < 4; ++p) AB[(rg+16*p)*65 + jl] = macc[p];
        __syncthreads();
    }

    // ---- blocked LDL^T: wave0 panel factor + trailing updates (verified) ----
    for (int pb = 0; pb < 4; ++pb) {
        const int kb = pb*16;
        if (tid < 64) {
            const int i = tid;
            double pr[16];
            #pragma unroll
            for (int c = 0; c < 16; ++c) pr[c] = AB[i*65 + kb + c];
            #pragma unroll
            for (int c = 0; c < 16; ++c) {
                const int k = kb + c;
                const double Dk = bcast64(pr[c], k);
                const double di = 1.0 / Dk;
                if (i == k) { dinv_s[k] = di; dvec_s[k] = Dk; }
                const double lik = pr[c] * di;
                #pragma unroll
                for (int j = c+1; j < 16; ++j) {
                    const double mkj = bcast64(pr[j], k);
                    if (i > k) pr[j] -= lik * mkj;
                }
                if (i > k) pr[c] = lik;
            }
            #pragma unroll
            for (int c = 0; c < 16; ++c) AB[i*65 + kb + c] = pr[c];
        }
        __syncthreads();
        const int lim = kb + 16;
        if (lim < 64) {
            double tacc[4] = {0.0, 0.0, 0.0, 0.0};
            #pragma unroll 4
            for (int c = 0; c < 16; ++c) {
                double lbv = AB[jl*65 + kb + c] * dvec_s[kb + c];
                #pragma unroll
                for (int p = 0; p < 4; ++p)
                    tacc[p] += AB[(rg+16*p)*65 + kb + c] * lbv;
            }
            if (jl >= lim) {
                #pragma unroll
                for (int p = 0; p < 4; ++p) {
                    int i = rg + 16*p;
                    if (i >= lim) AB[i*65 + jl] -= tacc[p];
                }
            }
        }
        __syncthreads();
    }

    // solves in wave0: L h = g ; h *= D^-1 ; L^T u = h
    if (tid < 64) {
        const int i = tid;
        double ha = ga_s[i], hb = gb_s[i];
        #pragma unroll
        for (int j = 0; j < 63; ++j) {
            double xa = bcast64(ha, j), xb = bcast64(hb, j);
            double lij = (i > j) ? AB[i*65+j] : 0.0;
            ha -= lij*xa; hb -= lij*xb;
        }
        double di = dinv_s[i];
        ha *= di; hb *= di;
        #pragma unroll
        for (int j = 63; j > 0; --j) {
            double xa = bcast64(ha, j), xb = bcast64(hb, j);
            double lji = (i < j) ? AB[j*65+i] : 0.0;
            ha -= lji*xa; hb -= lji*xb;
        }
        ua_s[i] = ha; ub_s[i] = hb;
    }
    __syncthreads();

    // s = A·u via areg wave reduction → sa_s/sb_s
    {
        double ra[4], rb[4];
        const double uaj = ua_s[jl], ubj = ub_s[jl];
        #pragma unroll
        for (int p = 0; p < 4; ++p) { ra[p] = areg[p]*uaj; rb[p] = areg[p]*ubj; }
        #pragma unroll
        for (int off = 32; off > 0; off >>= 1) {
            #pragma unroll
            for (int p = 0; p < 4; ++p) {
                ra[p] += __shfl_down(ra[p], off);
                rb[p] += __shfl_down(rb[p], off);
            }
        }
        if (jl == 0) {
            #pragma unroll
            for (int p = 0; p < 4; ++p) {
                sa_s[rg + 16*p] = ra[p];
                sb_s[rg + 16*p] = rb[p];
            }
        }
    }
    __syncthreads();

    // epilogue: S·sa, S·sb via sreg (coalesced, register-resident)
    {
        const int c16 = tid & 15, row16 = tid >> 4;
        double q1 = 0.0, q2 = 0.0;
        #pragma unroll
        for (int kk = 0; kk < 4; ++kk) {
            q1 += sreg[kk] * sa_s[4*c16 + kk];
            q2 += sreg[kk] * sb_s[4*c16 + kk];
        }
        q1 += __shfl_down(q1, 8, 16); q2 += __shfl_down(q2, 8, 16);
        q1 += __shfl_down(q1, 4, 16); q2 += __shfl_down(q2, 4, 16);
        q1 += __shfl_down(q1, 2, 16); q2 += __shfl_down(q2, 2, 16);
        q1 += __shfl_down(q1, 1, 16); q2 += __shfl_down(q2, 1, 16);
        if (c16 == 0) { PB[row16] = q1; PB[64 + row16] = q2; }
    }
    if (tid < 64) {
        double d1 = (eneg_s[tid] + sa_s[tid]) * t0b_s[tid];
        double d2 = sb_s[tid] * t0b_s[tid];
        #pragma unroll
        for (int off = 32; off > 0; off >>= 1) {
            d1 += __shfl_down(d1, off);
            d2 += __shfl_down(d2, off);
        }
        if (tid == 0) {
            double sw1 = swq[m] + swq[Bm + m];
            double sY = -d1;
            double sZ = sw1 - d2;
            lam_sh = ((double)qtot[m] - sY) / (1.0 - sZ);
        }
    }
    __syncthreads();
    if (tid < 64) {
        double p1 = t0a_s[tid] - PB[tid];
        double p2 = t0b_s[tid] - PB[64 + tid];
        outp[m*64 + tid] = (float)(p1 - lam_sh*p2);
    }
}

extern "C" void kernel_launch(void* const* d_in, const int* in_sizes, int n_in,
                              void* d_out, int out_size, void* d_ws, size_t ws_size,
                              hipStream_t stream) {
    const float* pos  = (const float*)d_in[0];
    const float* T    = (const float*)d_in[1];
    const float* eneg = (const float*)d_in[2];
    const float* nat  = (const float*)d_in[3];
    const float* qt   = (const float*)d_in[4];
    // d_in[5] 'p' unused
    const float* hard = (const float*)d_in[6];
    const float* covr = (const float*)d_in[7];
    const int*   an   = (const int*)d_in[8];
    const int*   eidx = (const int*)d_in[9];
    float* outp = (float*)d_out;
    (void)n_in; (void)out_size; (void)ws_size;

    const int B = in_sizes[4];
    double* ws = (double*)d_ws;   // B*8322*8 + 40 bytes

    k0_probe<<<dim3(1), dim3(64), 0, stream>>>(ws + (size_t)B*8322);
    k1_gram<<<dim3(2*B), dim3(256), 0, stream>>>(pos, T, eidx, ws);
    k2_solve<<<dim3(B), dim3(1024), 0, stream>>>(pos, nat, eneg, qt, hard,
                                                 covr, an, ws, outp);
}